// Round 1
// baseline (211.446 us; speedup 1.0000x reference)
//
#include <hip/hip_runtime.h>
#include <hip/hip_bf16.h>
#include <cstdint>
#include <type_traits>

#define N_NODES 50000
#define N_EDGES 800000
#define D_IN 128
#define D_HID 256
#define D_OUT 128

typedef __bf16 bf16;
typedef __bf16 bf16x8 __attribute__((ext_vector_type(8)));
typedef __bf16 bf16x4 __attribute__((ext_vector_type(4)));
typedef float f32x4 __attribute__((ext_vector_type(4)));

// ---------------------------------------------------------------------------
// Kernel 1: agg = (1+eps)*x  (float4), and convert/transpose weights to bf16.
// w1 [128][256] -> w1t [256][128] (n-major, k contiguous)
// w2 [256][128] -> w2t [128][256]
// grid: 6250 x 256 threads = 1.6M = N*D_IN/4 exactly.
// ---------------------------------------------------------------------------
__global__ __launch_bounds__(256) void prep_kernel(
    const float* __restrict__ x, const float* __restrict__ eps,
    const float* __restrict__ w1, const float* __restrict__ w2,
    float* __restrict__ agg, bf16* __restrict__ w1t, bf16* __restrict__ w2t) {
  const int i = blockIdx.x * 256 + threadIdx.x;
  const float scale = 1.0f + eps[0];
  const float4* x4 = (const float4*)x;
  float4* a4 = (float4*)agg;
  float4 v = x4[i];
  v.x *= scale; v.y *= scale; v.z *= scale; v.w *= scale;
  a4[i] = v;
  if (i < D_IN * D_HID) {            // 32768
    int k = i >> 8, n = i & 255;     // w1[k][n]
    w1t[n * D_IN + k] = (bf16)w1[i];
  } else if (i < 2 * D_IN * D_HID) { // next 32768
    int j = i - D_IN * D_HID;
    int k = j >> 7, n = j & 127;     // w2[k][n]
    w2t[n * D_HID + k] = (bf16)w2[j];
  }
}

// ---------------------------------------------------------------------------
// Kernel 2: segmented scatter-add over sorted edge_dst.
// One wave (64 lanes) per 64 contiguous edges; lane owns 2 channels (float2).
// Register-accumulate runs of equal dst; flush with fp32 atomics at run ends.
// grid: 3125 x 256 (4 waves/block) => 12500 waves * 64 edges = 800000 exact.
// ---------------------------------------------------------------------------
__global__ __launch_bounds__(256) void edge_agg_kernel(
    const float* __restrict__ x, const int* __restrict__ src,
    const int* __restrict__ dst, const float* __restrict__ val,
    float* __restrict__ agg) {
  const int wave = (blockIdx.x << 2) | (threadIdx.x >> 6);
  const int lane = threadIdx.x & 63;
  const long e0 = (long)wave * 64;
  if (e0 >= N_EDGES) return;
  const long e1 = (e0 + 64 < N_EDGES) ? e0 + 64 : N_EDGES;
  const float2* x2 = (const float2*)x;

  int cur = dst[e0];
  int d = cur;
  float vcur = val[e0];
  float2 xr = x2[(long)src[e0] * 64 + lane];
  float2 acc = make_float2(0.f, 0.f);

  for (long e = e0; e < e1; ++e) {
    // prefetch next edge (clamped on last iteration; values unused then)
    long en = (e + 1 < e1) ? e + 1 : e;
    int sn = src[en];
    int dn = dst[en];
    float vn = val[en];
    float2 xn = x2[(long)sn * 64 + lane];
    if (d != cur) {  // wave-uniform branch: flush previous run
      unsafeAtomicAdd(&agg[(long)cur * D_IN + lane * 2 + 0], acc.x);
      unsafeAtomicAdd(&agg[(long)cur * D_IN + lane * 2 + 1], acc.y);
      acc.x = 0.f; acc.y = 0.f;
      cur = d;
    }
    acc.x = fmaf(vcur, xr.x, acc.x);
    acc.y = fmaf(vcur, xr.y, acc.y);
    d = dn; vcur = vn; xr = xn;
  }
  unsafeAtomicAdd(&agg[(long)cur * D_IN + lane * 2 + 0], acc.x);
  unsafeAtomicAdd(&agg[(long)cur * D_IN + lane * 2 + 1], acc.y);
}

// ---------------------------------------------------------------------------
// Kernels 3/4: C[M,NOUT] = act(A[M,KDIM] @ Wt[NOUT,KDIM]^T + bias)
// MFMA f32_16x16x32_bf16. Block 256 thr (4 waves), tile M=64 x N=64,
// K staged in 128-chunks. LDS stride 136 (2-way bank aliasing only = free).
// Fragment layouts (m89/m91-verified family):
//   A: a[j] = A[lane&15][(lane>>4)*8 + j]
//   B: b[j] = B[(lane>>4)*8 + j][lane&15]   (we store B^T rows, read along K)
//   C: acc[r] -> row=(lane>>4)*4+r, col=lane&15
// ---------------------------------------------------------------------------
template <typename TA, int KDIM, int NOUT, bool RELU, typename TC>
__global__ __launch_bounds__(256) void mlp_gemm(
    const TA* __restrict__ A, const bf16* __restrict__ Wt,
    const float* __restrict__ bias, TC* __restrict__ C) {
  constexpr int BK = 128;
  constexpr int LDL = BK + 8;  // 136 bf16 = 272 B row stride
  __shared__ alignas(16) bf16 As[64][LDL];
  __shared__ alignas(16) bf16 Bs[64][LDL];

  const int tid = threadIdx.x;
  const int m0 = blockIdx.x * 64;
  const int n0 = blockIdx.y * 64;
  const int wave = tid >> 6;
  const int lane = tid & 63;
  const int wm = (wave >> 1) * 32;
  const int wn = (wave & 1) * 32;
  const int l15 = lane & 15;
  const int quad = lane >> 4;

  f32x4 acc[2][2] = {};

  for (int kt = 0; kt < KDIM; kt += BK) {
    // ---- stage A tile (64 rows x 128 k) as bf16 into As ----
    if constexpr (std::is_same_v<TA, float>) {
      #pragma unroll
      for (int it = 0; it < 8; ++it) {
        int idx = tid + it * 256;           // 0..2047
        int r = idx >> 5;                   // 32 float4 per row
        int c4 = (idx & 31) << 2;           // element col, step 4
        int row = m0 + r; if (row >= N_NODES) row = N_NODES - 1;
        float4 vv = *(const float4*)&A[(long)row * KDIM + kt + c4];
        bf16x4 pk = { (bf16)vv.x, (bf16)vv.y, (bf16)vv.z, (bf16)vv.w };
        *(bf16x4*)&As[r][c4] = pk;
      }
    } else {
      #pragma unroll
      for (int it = 0; it < 4; ++it) {
        int idx = tid + it * 256;           // 0..1023
        int r = idx >> 4;                   // 16 chunks of 8 bf16 per row
        int c8 = (idx & 15) << 3;
        int row = m0 + r; if (row >= N_NODES) row = N_NODES - 1;
        *(bf16x8*)&As[r][c8] = *(const bf16x8*)&A[(long)row * KDIM + kt + c8];
      }
    }
    // ---- stage B tile: Wt rows n0..n0+63, k in [kt,kt+128) ----
    #pragma unroll
    for (int it = 0; it < 4; ++it) {
      int idx = tid + it * 256;
      int r = idx >> 4;
      int c8 = (idx & 15) << 3;
      *(bf16x8*)&Bs[r][c8] = *(const bf16x8*)&Wt[(long)(n0 + r) * KDIM + kt + c8];
    }
    __syncthreads();

    #pragma unroll
    for (int ks = 0; ks < BK; ks += 32) {
      int kq = ks + quad * 8;
      bf16x8 af0 = *(const bf16x8*)&As[wm + l15][kq];
      bf16x8 af1 = *(const bf16x8*)&As[wm + 16 + l15][kq];
      bf16x8 bf0 = *(const bf16x8*)&Bs[wn + l15][kq];
      bf16x8 bf1 = *(const bf16x8*)&Bs[wn + 16 + l15][kq];
      acc[0][0] = __builtin_amdgcn_mfma_f32_16x16x32_bf16(af0, bf0, acc[0][0], 0, 0, 0);
      acc[0][1] = __builtin_amdgcn_mfma_f32_16x16x32_bf16(af0, bf1, acc[0][1], 0, 0, 0);
      acc[1][0] = __builtin_amdgcn_mfma_f32_16x16x32_bf16(af1, bf0, acc[1][0], 0, 0, 0);
      acc[1][1] = __builtin_amdgcn_mfma_f32_16x16x32_bf16(af1, bf1, acc[1][1], 0, 0, 0);
    }
    __syncthreads();
  }

  // ---- epilogue: bias (+ReLU), store ----
  #pragma unroll
  for (int mf = 0; mf < 2; ++mf) {
    #pragma unroll
    for (int nf = 0; nf < 2; ++nf) {
      int col = n0 + wn + nf * 16 + l15;
      float bv = bias[col];
      #pragma unroll
      for (int r = 0; r < 4; ++r) {
        int row = m0 + wm + mf * 16 + quad * 4 + r;
        if (row < N_NODES) {
          float vv = acc[mf][nf][r] + bv;
          if constexpr (RELU) vv = fmaxf(vv, 0.f);
          if constexpr (std::is_same_v<TC, float>)
            C[(long)row * NOUT + col] = vv;
          else
            C[(long)row * NOUT + col] = (bf16)vv;
        }
      }
    }
  }
}

// ---------------------------------------------------------------------------
extern "C" void kernel_launch(void* const* d_in, const int* in_sizes, int n_in,
                              void* d_out, int out_size, void* d_ws, size_t ws_size,
                              hipStream_t stream) {
  const float* x    = (const float*)d_in[0];
  const int*   esrc = (const int*)d_in[1];
  const int*   edst = (const int*)d_in[2];
  const float* evl  = (const float*)d_in[3];
  const float* eps  = (const float*)d_in[4];
  const float* w1   = (const float*)d_in[5];
  const float* b1   = (const float*)d_in[6];
  const float* w2   = (const float*)d_in[7];
  const float* b2   = (const float*)d_in[8];
  float* out = (float*)d_out;

  // workspace layout (all 16B aligned)
  float* agg = (float*)d_ws;                                   // 25.6 MB
  bf16*  h   = (bf16*)((char*)d_ws + (size_t)N_NODES * D_IN * 4); // 25.6 MB
  bf16*  w1t = h + (size_t)N_NODES * D_HID;                    // 64 KB
  bf16*  w2t = w1t + D_IN * D_HID;                             // 64 KB

  prep_kernel<<<(N_NODES * D_IN / 4) / 256, 256, 0, stream>>>(x, eps, w1, w2, agg, w1t, w2t);
  edge_agg_kernel<<<N_EDGES / 256, 256, 0, stream>>>(x, esrc, edst, evl, agg);
  mlp_gemm<float, D_IN, D_HID, true, bf16>
      <<<dim3((N_NODES + 63) / 64, D_HID / 64), 256, 0, stream>>>(agg, w1t, b1, h);
  mlp_gemm<bf16, D_HID, D_OUT, false, float>
      <<<dim3((N_NODES + 63) / 64, D_OUT / 64), 256, 0, stream>>>(h, w2t, b2, out);
}